// Round 1
// baseline (758.468 us; speedup 1.0000x reference)
//
#include <hip/hip_runtime.h>
#include <math.h>

// Problem constants
#define FD   256
#define NH   4
#define SP3  8
#define NP   32          // SP3*NH aux points per query
#define EDIM 64          // FD/NH
#define H    128
#define NS   1024
#define BS   4
#define QB   4           // queries per block

#define BATCH_ELEMS (H*H*FD)          // per (plane,b): 128*128*256
#define PLANE_ELEMS (BS*BATCH_ELEMS)  // per plane: 4*128*128*256 = 4,194,304 floats (16.78 MB)

// ---------------------------------------------------------------------------
// Kernel A: transpose planes [B,C,H,W] -> [B,H*W,C] (channel-last) so that a
// bilinear corner read of all 256 channels is one contiguous 1KB vector.
// ---------------------------------------------------------------------------
__global__ __launch_bounds__(256) void transpose_planes(
    const float* __restrict__ xz, const float* __restrict__ xy,
    const float* __restrict__ yz, float* __restrict__ out)
{
  int bid = blockIdx.x;
  int tTile = bid & 255; bid >>= 8;   // 256 tiles of 64 texels
  int cTile = bid & 3;   bid >>= 2;   // 4 tiles of 64 channels
  int b     = bid & 3;   bid >>= 2;   // 4 batches
  int plane = bid;                    // 0..2
  const float* src = plane == 0 ? xz : (plane == 1 ? xy : yz);
  float* dst = out + (size_t)plane * PLANE_ELEMS;

  __shared__ float T[64][65];
  int lane = threadIdx.x & 63, w = threadIdx.x >> 6;

  const float* s = src + ((size_t)b * FD + cTile * 64) * (H * H) + tTile * 64;
  #pragma unroll
  for (int i = 0; i < 16; i++) {
    int cl = w * 16 + i;
    T[cl][lane] = s[(size_t)cl * (H * H) + lane];
  }
  __syncthreads();
  float* d = dst + ((size_t)b * (H * H) + tTile * 64) * FD + cTile * 64;
  #pragma unroll
  for (int i = 0; i < 16; i++) {
    int tl = w * 16 + i;
    d[(size_t)tl * FD + lane] = T[lane][tl];   // stride 65 -> conflict-free
  }
}

// ---------------------------------------------------------------------------
// Bilinear helpers (channel-last plane, pointer pre-offset by channel)
// ---------------------------------------------------------------------------
__device__ __forceinline__ float sample_plane(const float* __restrict__ p,
                                              float u, float v) {
  float x = fminf(fmaxf(u, 0.f), 1.f) * (float)(H - 1);
  float y = fminf(fmaxf(v, 0.f), 1.f) * (float)(H - 1);
  float xf = floorf(x), yf = floorf(y);
  int x0 = (int)xf, y0 = (int)yf;
  float wx = x - xf, wy = y - yf;
  int dx = (x0 < H - 1) ? FD : 0;
  int dy = (y0 < H - 1) ? H * FD : 0;
  int i00 = (y0 * H + x0) * FD;
  float f00 = p[i00], f01 = p[i00 + dx], f10 = p[i00 + dy], f11 = p[i00 + dy + dx];
  float a = f00 + wx * (f01 - f00);
  float b = f10 + wx * (f11 - f10);
  return a + wy * (b - a);
}

__device__ __forceinline__ void setup_samp(int* si, float* sw, float u, float v) {
  float x = fminf(fmaxf(u, 0.f), 1.f) * (float)(H - 1);
  float y = fminf(fmaxf(v, 0.f), 1.f) * (float)(H - 1);
  float xf = floorf(x), yf = floorf(y);
  int x0 = (int)xf, y0 = (int)yf;
  float wx = x - xf, wy = y - yf;
  si[0] = (y0 * H + x0) * FD;
  si[1] = (x0 < H - 1) ? FD : 0;
  si[2] = (y0 < H - 1) ? H * FD : 0;
  sw[0] = (1.f - wy) * (1.f - wx);
  sw[1] = (1.f - wy) * wx;
  sw[2] = wy * (1.f - wx);
  sw[3] = wy * wx;
}

__device__ __forceinline__ float bil(const float* __restrict__ p,
                                     const int* si, const float* sw) {
  int i00 = si[0], dx = si[1], dy = si[2];
  float f00 = p[i00], f01 = p[i00 + dx], f10 = p[i00 + dy], f11 = p[i00 + dy + dx];
  return fmaf(sw[0], f00, fmaf(sw[1], f01, fmaf(sw[2], f10, sw[3] * f11)));
}

// ---------------------------------------------------------------------------
// Kernel B: fully fused deformable attention, 4 queries per 256-thread block.
// Thread tid == channel c for all 256-wide vectors.
// Key algebra: sim = (q @ w_k^T) . aux_feat   (never materialize k)
//              out_head = (sum_j attn_j * aux_feat_j) @ w_v   (v collapsed)
// ---------------------------------------------------------------------------
__global__ __launch_bounds__(256) void deform_attn(
    const float* __restrict__ qpos, const float* __restrict__ planesT,
    const float* __restrict__ w_off, const float* __restrict__ b_off,
    const float* __restrict__ w_q, const float* __restrict__ b_q,
    const float* __restrict__ w_k, const float* __restrict__ b_k,
    const float* __restrict__ w_v, const float* __restrict__ b_v,
    const float* __restrict__ w_out, const float* __restrict__ b_out,
    float* __restrict__ out)
{
  const int tid  = threadIdx.x;
  const int lane = tid & 63;
  const int wid  = tid >> 6;
  const int q0   = blockIdx.x * QB;
  const int b    = q0 / NS;

  __shared__ float s_feat[QB][FD];
  __shared__ float s_aux[QB][NP][3];
  __shared__ float s_q[QB][EDIM];
  __shared__ float s_qbk[QB];
  __shared__ int   s_sidx[QB][NP][3][3];
  __shared__ float s_swt[QB][NP][3][4];
  __shared__ float s_part[NP][4];
  __shared__ float s_attn[NP];
  __shared__ float s_wf[QB][NH * FD];
  __shared__ float s_o[QB][FD];

  const float* Pxz = planesT + 0 * (size_t)PLANE_ELEMS + (size_t)b * BATCH_ELEMS + tid;
  const float* Pxy = planesT + 1 * (size_t)PLANE_ELEMS + (size_t)b * BATCH_ELEMS + tid;
  const float* Pyz = planesT + 2 * (size_t)PLANE_ELEMS + (size_t)b * BATCH_ELEMS + tid;

  // ---- P1: feature = triplane(query_pos), thread c handles channel c ------
  #pragma unroll
  for (int qi = 0; qi < QB; ++qi) {
    float px = qpos[(q0 + qi) * 3 + 0];
    float py = qpos[(q0 + qi) * 3 + 1];
    float pz = qpos[(q0 + qi) * 3 + 2];
    float f = sample_plane(Pxz, px, pz)
            + sample_plane(Pxy, px, py)
            + sample_plane(Pyz, py, pz);
    s_feat[qi][tid] = f;
  }
  __syncthreads();

  // ---- P2: off = feature@w_off + b_off; aux = off + query_pos -------------
  if (tid < 192) {
    int qg = tid / 96;          // query pair {qg, qg+2}
    int j  = tid % 96;
    float a0 = b_off[j], a1 = a0;
    for (int c = 0; c < FD; c++) {
      float w = w_off[c * 96 + j];
      a0 = fmaf(s_feat[qg][c], w, a0);
      a1 = fmaf(s_feat[qg + 2][c], w, a1);
    }
    int p = j / 3, d = j % 3;
    s_aux[qg][p][d]     = a0 + qpos[(q0 + qg) * 3 + d];
    s_aux[qg + 2][p][d] = a1 + qpos[(q0 + qg + 2) * 3 + d];
  }
  __syncthreads();

  // ---- P3a: q projection (scaled by sqrt(E)=8), wave handles one query ----
  {
    int qi = wid, e = lane;
    float a = b_q[e];
    for (int c = 0; c < FD; c++) a = fmaf(s_feat[qi][c], w_q[c * EDIM + e], a);
    s_q[qi][e] = a * 8.0f;
  }
  // ---- P2b: precompute per-point sampling params (indices + weights) ------
  if (tid < QB * NP) {
    int qi = tid >> 5, p = tid & 31;
    float ax = s_aux[qi][p][0], ay = s_aux[qi][p][1], az = s_aux[qi][p][2];
    setup_samp(s_sidx[qi][p][0], s_swt[qi][p][0], ax, az);  // xz plane
    setup_samp(s_sidx[qi][p][1], s_swt[qi][p][1], ax, ay);  // xy plane
    setup_samp(s_sidx[qi][p][2], s_swt[qi][p][2], ay, az);  // yz plane
  }
  __syncthreads();

  // ---- P3b: qk[c] = sum_e q_scaled[e] * w_k[c,e] (per thread, 4 queries) --
  float qk0 = 0.f, qk1 = 0.f, qk2 = 0.f, qk3 = 0.f;
  {
    const float4* wk4 = reinterpret_cast<const float4*>(w_k + tid * EDIM);
    #pragma unroll
    for (int e4 = 0; e4 < EDIM / 4; e4++) {
      float4 w = wk4[e4];
      int e = e4 * 4;
      qk0 = fmaf(s_q[0][e], w.x, qk0); qk0 = fmaf(s_q[0][e+1], w.y, qk0);
      qk0 = fmaf(s_q[0][e+2], w.z, qk0); qk0 = fmaf(s_q[0][e+3], w.w, qk0);
      qk1 = fmaf(s_q[1][e], w.x, qk1); qk1 = fmaf(s_q[1][e+1], w.y, qk1);
      qk1 = fmaf(s_q[1][e+2], w.z, qk1); qk1 = fmaf(s_q[1][e+3], w.w, qk1);
      qk2 = fmaf(s_q[2][e], w.x, qk2); qk2 = fmaf(s_q[2][e+1], w.y, qk2);
      qk2 = fmaf(s_q[2][e+2], w.z, qk2); qk2 = fmaf(s_q[2][e+3], w.w, qk2);
      qk3 = fmaf(s_q[3][e], w.x, qk3); qk3 = fmaf(s_q[3][e+1], w.y, qk3);
      qk3 = fmaf(s_q[3][e+2], w.z, qk3); qk3 = fmaf(s_q[3][e+3], w.w, qk3);
    }
  }
  // qbk[qi] = q_scaled . b_k (constant added to every sim logit)
  if (tid < QB) {
    float a = 0.f;
    for (int e = 0; e < EDIM; e++) a = fmaf(s_q[tid][e], b_k[e], a);
    s_qbk[tid] = a;
  }
  __syncthreads();

  // ---- P4: per query: sample 32 aux points, sim, softmax, weighted feat ---
  float af[NP];
  for (int qi = 0; qi < QB; ++qi) {
    float qkq = qi == 0 ? qk0 : qi == 1 ? qk1 : qi == 2 ? qk2 : qk3;
    #pragma unroll
    for (int p = 0; p < NP; p++) {
      float v = bil(Pxz, s_sidx[qi][p][0], s_swt[qi][p][0])
              + bil(Pxy, s_sidx[qi][p][1], s_swt[qi][p][1])
              + bil(Pyz, s_sidx[qi][p][2], s_swt[qi][p][2]);
      af[p] = v;
      float t = qkq * v;
      #pragma unroll
      for (int o = 32; o >= 1; o >>= 1) t += __shfl_xor(t, o, 64);
      if (lane == 0) s_part[p][wid] = t;
    }
    __syncthreads();
    if (tid < NH) {
      float sim[SP3], m = -1e30f;
      #pragma unroll
      for (int j = 0; j < SP3; j++) {
        int p = j * NH + tid;
        float s = s_part[p][0] + s_part[p][1] + s_part[p][2] + s_part[p][3] + s_qbk[qi];
        sim[j] = s; m = fmaxf(m, s);
      }
      float sum = 0.f, e_[SP3];
      #pragma unroll
      for (int j = 0; j < SP3; j++) { e_[j] = __expf(sim[j] - m); sum += e_[j]; }
      float inv = 1.0f / sum;
      #pragma unroll
      for (int j = 0; j < SP3; j++) s_attn[j * NH + tid] = e_[j] * inv;
    }
    __syncthreads();
    float wf0 = 0.f, wf1 = 0.f, wf2 = 0.f, wf3 = 0.f;
    #pragma unroll
    for (int j = 0; j < SP3; j++) {
      wf0 = fmaf(s_attn[j * NH + 0], af[j * NH + 0], wf0);
      wf1 = fmaf(s_attn[j * NH + 1], af[j * NH + 1], wf1);
      wf2 = fmaf(s_attn[j * NH + 2], af[j * NH + 2], wf2);
      wf3 = fmaf(s_attn[j * NH + 3], af[j * NH + 3], wf3);
    }
    s_wf[qi][0 * FD + tid] = wf0;
    s_wf[qi][1 * FD + tid] = wf1;
    s_wf[qi][2 * FD + tid] = wf2;
    s_wf[qi][3 * FD + tid] = wf3;
    __syncthreads();
  }

  // ---- P5: out_head = wfeat @ w_v + b_v (wave wid = head, lane = e) -------
  {
    int nh = wid, e = lane;
    float a0 = b_v[e], a1 = b_v[e], a2 = b_v[e], a3 = b_v[e];
    for (int c = 0; c < FD; c++) {
      float w = w_v[c * EDIM + e];
      a0 = fmaf(s_wf[0][nh * FD + c], w, a0);
      a1 = fmaf(s_wf[1][nh * FD + c], w, a1);
      a2 = fmaf(s_wf[2][nh * FD + c], w, a2);
      a3 = fmaf(s_wf[3][nh * FD + c], w, a3);
    }
    s_o[0][nh * EDIM + e] = a0;
    s_o[1][nh * EDIM + e] = a1;
    s_o[2][nh * EDIM + e] = a2;
    s_o[3][nh * EDIM + e] = a3;
  }
  __syncthreads();

  // ---- P6: final = o @ w_out + b_out + feature ----------------------------
  {
    float r0 = b_out[tid] + s_feat[0][tid];
    float r1 = b_out[tid] + s_feat[1][tid];
    float r2 = b_out[tid] + s_feat[2][tid];
    float r3 = b_out[tid] + s_feat[3][tid];
    for (int cp = 0; cp < FD; cp++) {
      float w = w_out[cp * FD + tid];
      r0 = fmaf(s_o[0][cp], w, r0);
      r1 = fmaf(s_o[1][cp], w, r1);
      r2 = fmaf(s_o[2][cp], w, r2);
      r3 = fmaf(s_o[3][cp], w, r3);
    }
    out[(size_t)(q0 + 0) * FD + tid] = r0;
    out[(size_t)(q0 + 1) * FD + tid] = r1;
    out[(size_t)(q0 + 2) * FD + tid] = r2;
    out[(size_t)(q0 + 3) * FD + tid] = r3;
  }
}

// ---------------------------------------------------------------------------
extern "C" void kernel_launch(void* const* d_in, const int* in_sizes, int n_in,
                              void* d_out, int out_size, void* d_ws, size_t ws_size,
                              hipStream_t stream) {
  const float* qp    = (const float*)d_in[0];
  const float* cxz   = (const float*)d_in[1];
  const float* cxy   = (const float*)d_in[2];
  const float* cyz   = (const float*)d_in[3];
  const float* w_off = (const float*)d_in[4];
  const float* b_off = (const float*)d_in[5];
  const float* w_q   = (const float*)d_in[6];
  const float* b_q   = (const float*)d_in[7];
  const float* w_k   = (const float*)d_in[8];
  const float* b_k   = (const float*)d_in[9];
  const float* w_v   = (const float*)d_in[10];
  const float* b_v   = (const float*)d_in[11];
  const float* w_out = (const float*)d_in[12];
  const float* b_out = (const float*)d_in[13];
  float* out = (float*)d_out;

  // ws: 3 transposed fp32 planes = 50.33 MB (re-built every launch; ws is
  // re-poisoned before each timed call).
  float* planesT = (float*)d_ws;
  (void)ws_size; (void)in_sizes; (void)n_in; (void)out_size;

  hipLaunchKernelGGL(transpose_planes, dim3(3 * 4 * 4 * 256), dim3(256), 0, stream,
                     cxz, cxy, cyz, planesT);
  hipLaunchKernelGGL(deform_attn, dim3(BS * NS / QB), dim3(256), 0, stream,
                     qp, planesT,
                     w_off, b_off, w_q, b_q, w_k, b_k, w_v, b_v, w_out, b_out,
                     out);
}

// Round 3
// 551.993 us; speedup vs baseline: 1.3741x; 1.3741x over previous
//
#include <hip/hip_runtime.h>
#include <math.h>

// Problem constants
#define FD   256
#define NH   4
#define SP3  8
#define NP   32          // SP3*NH aux points per query
#define EDIM 64          // FD/NH
#define H    128
#define NS   1024
#define BS   4
#define QT   8           // queries per tile-block (featk / epik)

#define TEX         (H*H)              // 16384 texels per (plane,b)
#define BATCH_ELEMS (TEX*FD)           // 4,194,304 floats
#define PAIR_B      2                  // batches processed per pass
#define PAIR_Q      (PAIR_B*NS)        // 2048 queries per pass
#define PPLANE      (PAIR_B*BATCH_ELEMS) // per-plane elems in pair buffer

// ---- workspace layout (float offsets). Total 28,508,160 floats = 114.03 MB.
// Round 1 proved ws_size >= 201.3 MB; round 2's 228 MB overflowed and
// corrupted the harness's pristine input copies (post-timing divergence).
#define WS_PLANES 0
#define WS_FEAT   (3*PPLANE)                       // [2048][256]
#define WS_QK     (WS_FEAT + PAIR_Q*FD)            // [2048][256]
#define WS_AUX    (WS_QK   + PAIR_Q*FD)            // [2048][96]
#define WS_WF     (WS_AUX  + PAIR_Q*NP*3)          // [2048][4][256]

// ---------------------------------------------------------------------------
// K1: transpose planes [B,C,H,W] -> [b-pair][H*W,C] (channel-last).
// Reads: float4 over texels (4x256B segs/wave); writes 1KB contiguous/wave.
// ---------------------------------------------------------------------------
__global__ __launch_bounds__(256) void tpk2(
    const float* __restrict__ xz, const float* __restrict__ xy,
    const float* __restrict__ yz, float* __restrict__ dstAll, int b0)
{
  int bid = blockIdx.x;
  int tT = bid & 255; bid >>= 8;     // 256 texel-tiles of 64
  int bl = bid & 1;   bid >>= 1;     // local batch in pair
  int pl = bid;                      // plane
  const float* src = pl == 0 ? xz : (pl == 1 ? xy : yz);
  float* dst = dstAll + (size_t)pl * PPLANE + (size_t)bl * BATCH_ELEMS;
  int b = b0 + bl;

  __shared__ float T[64 * 260];      // T[texel][channel], stride 260
  int lane = threadIdx.x & 63, w = threadIdx.x >> 6;
  int lrow = lane >> 4;              // 0..3
  int ltex = (lane & 15) << 2;       // 0,4,..,60

  const float* sbase = src + (size_t)b * FD * TEX + tT * 64;
  #pragma unroll
  for (int i = 0; i < 16; i++) {
    int c = i * 16 + w * 4 + lrow;   // covers 0..255
    float4 v = *(const float4*)(sbase + (size_t)c * TEX + ltex);
    T[(ltex + 0) * 260 + c] = v.x;
    T[(ltex + 1) * 260 + c] = v.y;
    T[(ltex + 2) * 260 + c] = v.z;
    T[(ltex + 3) * 260 + c] = v.w;
  }
  __syncthreads();
  #pragma unroll
  for (int i = 0; i < 16; i++) {
    int t = w * 16 + i;
    float4 v = *(const float4*)(&T[t * 260 + lane * 4]);
    *(float4*)(dst + (size_t)(tT * 64 + t) * FD + lane * 4) = v;  // 1KB/wave
  }
}

// ---------------------------------------------------------------------------
// Bilinear helpers (channel-last plane, pointer pre-offset by channel)
// ---------------------------------------------------------------------------
__device__ __forceinline__ float sample_plane(const float* __restrict__ p,
                                              float u, float v) {
  float x = fminf(fmaxf(u, 0.f), 1.f) * (float)(H - 1);
  float y = fminf(fmaxf(v, 0.f), 1.f) * (float)(H - 1);
  float xf = floorf(x), yf = floorf(y);
  int x0 = (int)xf, y0 = (int)yf;
  float wx = x - xf, wy = y - yf;
  int dx = (x0 < H - 1) ? FD : 0;
  int dy = (y0 < H - 1) ? H * FD : 0;
  int i00 = (y0 * H + x0) * FD;
  float f00 = p[i00], f01 = p[i00 + dx], f10 = p[i00 + dy], f11 = p[i00 + dy + dx];
  float a = f00 + wx * (f01 - f00);
  float b = f10 + wx * (f11 - f10);
  return a + wy * (b - a);
}

__device__ __forceinline__ void setup_samp(int* si, float* sw, float u, float v) {
  float x = fminf(fmaxf(u, 0.f), 1.f) * (float)(H - 1);
  float y = fminf(fmaxf(v, 0.f), 1.f) * (float)(H - 1);
  float xf = floorf(x), yf = floorf(y);
  int x0 = (int)xf, y0 = (int)yf;
  float wx = x - xf, wy = y - yf;
  si[0] = (y0 * H + x0) * FD;
  si[1] = (x0 < H - 1) ? FD : 0;
  si[2] = (y0 < H - 1) ? H * FD : 0;
  sw[0] = (1.f - wy) * (1.f - wx);
  sw[1] = (1.f - wy) * wx;
  sw[2] = wy * (1.f - wx);
  sw[3] = wy * wx;
}

__device__ __forceinline__ float bil(const float* __restrict__ p,
                                     const int* si, const float* sw) {
  int i00 = si[0], dx = si[1], dy = si[2];
  float f00 = p[i00], f01 = p[i00 + dx], f10 = p[i00 + dy], f11 = p[i00 + dy + dx];
  return fmaf(sw[0], f00, fmaf(sw[1], f01, fmaf(sw[2], f10, sw[3] * f11)));
}

// ---------------------------------------------------------------------------
// K2: per 8-query tile: feature sampling + offsets/aux + q-projection + qk.
// qk[q][c] = sum_e q_scaled[e] * w_k[c][e];  (q . b_k cancels in softmax)
// ---------------------------------------------------------------------------
__global__ __launch_bounds__(256) void featk(
    const float* __restrict__ qpos, const float* __restrict__ planesT,
    const float* __restrict__ w_off, const float* __restrict__ b_off,
    const float* __restrict__ w_q, const float* __restrict__ b_q,
    const float* __restrict__ w_k,
    float* __restrict__ feat, float* __restrict__ aux, float* __restrict__ qk,
    int b0)
{
  const int tid = threadIdx.x;
  const int q0l = blockIdx.x * QT;          // local query base in pair
  const int bl = q0l >> 10;                 // local batch
  __shared__ float s_feat[QT * 260];
  __shared__ float s_q[QT * 68];

  const float* Pxz = planesT + 0 * (size_t)PPLANE + (size_t)bl * BATCH_ELEMS + tid;
  const float* Pxy = planesT + 1 * (size_t)PPLANE + (size_t)bl * BATCH_ELEMS + tid;
  const float* Pyz = planesT + 2 * (size_t)PPLANE + (size_t)bl * BATCH_ELEMS + tid;

  for (int qs = 0; qs < QT; qs++) {
    size_t qg = (size_t)b0 * NS + q0l + qs; // global query for qpos
    float px = qpos[qg * 3 + 0], py = qpos[qg * 3 + 1], pz = qpos[qg * 3 + 2];
    float f = sample_plane(Pxz, px, pz) + sample_plane(Pxy, px, py)
            + sample_plane(Pyz, py, pz);
    s_feat[qs * 260 + tid] = f;
    feat[(size_t)(q0l + qs) * FD + tid] = f;
  }
  __syncthreads();

  // offsets -> aux. thread t<192: half=t/96 handles 4 queries for column j.
  if (tid < 192) {
    int half = tid / 96, j = tid - half * 96;
    float acc[4];
    float bj = b_off[j];
    #pragma unroll
    for (int k = 0; k < 4; k++) acc[k] = bj;
    for (int c = 0; c < FD; c++) {
      float wv = w_off[c * 96 + j];
      #pragma unroll
      for (int k = 0; k < 4; k++)
        acc[k] = fmaf(s_feat[(half * 4 + k) * 260 + c], wv, acc[k]);
    }
    int d = j % 3;
    #pragma unroll
    for (int k = 0; k < 4; k++) {
      int qs = half * 4 + k;
      size_t qg = (size_t)b0 * NS + q0l + qs;
      aux[(size_t)(q0l + qs) * 96 + j] = acc[k] + qpos[qg * 3 + d];
    }
  }
  // q projection (scaled by sqrt(E)=8); wave g handles queries g*2, g*2+1
  {
    int e = tid & 63, g = tid >> 6;
    #pragma unroll
    for (int k = 0; k < 2; k++) {
      int qs = g * 2 + k;
      float a = b_q[e];
      for (int c = 0; c < FD; c++)
        a = fmaf(s_feat[qs * 260 + c], w_q[c * EDIM + e], a);
      s_q[qs * 68 + e] = a * 8.0f;
    }
  }
  __syncthreads();
  // qk: thread owns channel tid; w_k row contiguous (float4)
  {
    float acc[QT];
    #pragma unroll
    for (int qs = 0; qs < QT; qs++) acc[qs] = 0.f;
    const float4* wk4 = reinterpret_cast<const float4*>(w_k + (size_t)tid * EDIM);
    for (int e4 = 0; e4 < EDIM / 4; e4++) {
      float4 wv = wk4[e4];
      int e = e4 * 4;
      #pragma unroll
      for (int qs = 0; qs < QT; qs++) {
        acc[qs] = fmaf(s_q[qs * 68 + e + 0], wv.x, acc[qs]);
        acc[qs] = fmaf(s_q[qs * 68 + e + 1], wv.y, acc[qs]);
        acc[qs] = fmaf(s_q[qs * 68 + e + 2], wv.z, acc[qs]);
        acc[qs] = fmaf(s_q[qs * 68 + e + 3], wv.w, acc[qs]);
      }
    }
    #pragma unroll
    for (int qs = 0; qs < QT; qs++)
      qk[(size_t)(q0l + qs) * FD + tid] = acc[qs];
  }
}

// ---------------------------------------------------------------------------
// K3 (hot): one query per block. Sample 32 aux points x 3 planes, sim via
// cross-lane reduction, softmax per head, attention-weighted feature -> wf.
// No weight matrices touched here.
// ---------------------------------------------------------------------------
__global__ __launch_bounds__(256) void attnk(
    const float* __restrict__ planesT, const float* __restrict__ aux,
    const float* __restrict__ qk, float* __restrict__ wf)
{
  const int tid = threadIdx.x, lane = tid & 63, wid = tid >> 6;
  const int q = blockIdx.x;                 // local query in pair
  const int bl = q >> 10;

  __shared__ int   s_si[96][3];
  __shared__ float s_sw[96][4];
  __shared__ float s_af[NP * 260];
  __shared__ float s_part[NP][4];
  __shared__ float s_attn[NP];

  const float* Pxz = planesT + (size_t)bl * BATCH_ELEMS + tid;
  const float* Pxy = Pxz + (size_t)PPLANE;
  const float* Pyz = Pxy + (size_t)PPLANE;

  if (tid < 96) {
    int p = tid / 3, pl = tid - p * 3;
    float ax = aux[(size_t)q * 96 + p * 3 + 0];
    float ay = aux[(size_t)q * 96 + p * 3 + 1];
    float az = aux[(size_t)q * 96 + p * 3 + 2];
    float u = (pl == 2) ? ay : ax;   // pl0:(ax,az) pl1:(ax,ay) pl2:(ay,az)
    float v = (pl == 1) ? ay : az;
    setup_samp(s_si[tid], s_sw[tid], u, v);
  }
  float qkc = qk[(size_t)q * FD + tid];
  __syncthreads();

  #pragma unroll 4
  for (int p = 0; p < NP; p++) {
    float v = bil(Pxz, s_si[p * 3 + 0], s_sw[p * 3 + 0])
            + bil(Pxy, s_si[p * 3 + 1], s_sw[p * 3 + 1])
            + bil(Pyz, s_si[p * 3 + 2], s_sw[p * 3 + 2]);
    s_af[p * 260 + tid] = v;
    float t = qkc * v;
    #pragma unroll
    for (int o = 32; o >= 1; o >>= 1) t += __shfl_xor(t, o, 64);
    if (lane == 0) s_part[p][wid] = t;
  }
  __syncthreads();

  if (tid < NH) {
    float sim[SP3], m = -1e30f;
    #pragma unroll
    for (int j = 0; j < SP3; j++) {
      int p = j * NH + tid;
      float s = s_part[p][0] + s_part[p][1] + s_part[p][2] + s_part[p][3];
      sim[j] = s; m = fmaxf(m, s);
    }
    float sum = 0.f, e_[SP3];
    #pragma unroll
    for (int j = 0; j < SP3; j++) { e_[j] = __expf(sim[j] - m); sum += e_[j]; }
    float inv = 1.0f / sum;
    #pragma unroll
    for (int j = 0; j < SP3; j++) s_attn[j * NH + tid] = e_[j] * inv;
  }
  __syncthreads();

  float w0 = 0.f, w1 = 0.f, w2 = 0.f, w3 = 0.f;
  #pragma unroll
  for (int j = 0; j < SP3; j++) {
    w0 = fmaf(s_attn[j * NH + 0], s_af[(j * NH + 0) * 260 + tid], w0);
    w1 = fmaf(s_attn[j * NH + 1], s_af[(j * NH + 1) * 260 + tid], w1);
    w2 = fmaf(s_attn[j * NH + 2], s_af[(j * NH + 2) * 260 + tid], w2);
    w3 = fmaf(s_attn[j * NH + 3], s_af[(j * NH + 3) * 260 + tid], w3);
  }
  wf[((size_t)q * NH + 0) * FD + tid] = w0;
  wf[((size_t)q * NH + 1) * FD + tid] = w1;
  wf[((size_t)q * NH + 2) * FD + tid] = w2;
  wf[((size_t)q * NH + 3) * FD + tid] = w3;
}

// ---------------------------------------------------------------------------
// K4: epilogue per 8-query tile: o = per-head wf@w_v + b_v (w_v in LDS),
// then out = o@w_out + b_out + feat (w_out streamed once per block).
// ---------------------------------------------------------------------------
__global__ __launch_bounds__(256) void epik(
    const float* __restrict__ wf, const float* __restrict__ feat,
    const float* __restrict__ w_v, const float* __restrict__ b_v,
    const float* __restrict__ w_out, const float* __restrict__ b_out,
    float* __restrict__ out, int b0)
{
  const int tid = threadIdx.x;
  const int q0l = blockIdx.x * QT;
  __shared__ float s_wv[FD * EDIM];   // 64 KB, [c][e]
  __shared__ float s_o[QT * 257];

  {
    const float4* src4 = (const float4*)w_v;
    float4* dst4 = (float4*)s_wv;
    #pragma unroll
    for (int i = 0; i < (FD * EDIM / 4) / 256; i++)
      dst4[tid + 256 * i] = src4[tid + 256 * i];
  }
  __syncthreads();

  { // phase A: o[qs][h*64+e]
    int h = tid >> 6, e = tid & 63;
    float acc[QT];
    float bv = b_v[e];
    #pragma unroll
    for (int qs = 0; qs < QT; qs++) acc[qs] = bv;
    const float* wrow = wf + ((size_t)q0l * NH + h) * FD;
    for (int c = 0; c < FD; c++) {
      float wv = s_wv[c * EDIM + e];
      #pragma unroll
      for (int qs = 0; qs < QT; qs++)
        acc[qs] = fmaf(wrow[(size_t)qs * NH * FD + c], wv, acc[qs]);
    }
    #pragma unroll
    for (int qs = 0; qs < QT; qs++) s_o[qs * 257 + h * EDIM + e] = acc[qs];
  }
  __syncthreads();

  { // phase B: out[q][d] = sum_c o[q][c] w_out[c][d] + b_out[d] + feat[q][d]
    float r[QT];
    float bo = b_out[tid];
    #pragma unroll
    for (int qs = 0; qs < QT; qs++) r[qs] = bo;
    for (int c = 0; c < FD; c++) {
      float wv = w_out[(size_t)c * FD + tid];
      #pragma unroll
      for (int qs = 0; qs < QT; qs++)
        r[qs] = fmaf(s_o[qs * 257 + c], wv, r[qs]);
    }
    #pragma unroll
    for (int qs = 0; qs < QT; qs++)
      out[((size_t)b0 * NS + q0l + qs) * FD + tid]
          = r[qs] + feat[(size_t)(q0l + qs) * FD + tid];
  }
}

// ---------------------------------------------------------------------------
extern "C" void kernel_launch(void* const* d_in, const int* in_sizes, int n_in,
                              void* d_out, int out_size, void* d_ws, size_t ws_size,
                              hipStream_t stream) {
  const float* qp    = (const float*)d_in[0];
  const float* cxz   = (const float*)d_in[1];
  const float* cxy   = (const float*)d_in[2];
  const float* cyz   = (const float*)d_in[3];
  const float* w_off = (const float*)d_in[4];
  const float* b_off = (const float*)d_in[5];
  const float* w_q   = (const float*)d_in[6];
  const float* b_q   = (const float*)d_in[7];
  const float* w_k   = (const float*)d_in[8];
  const float* b_k   = (const float*)d_in[9];   (void)b_k; // cancels in softmax
  const float* w_v   = (const float*)d_in[10];
  const float* b_v   = (const float*)d_in[11];
  const float* w_out = (const float*)d_in[12];
  const float* b_out = (const float*)d_in[13];
  float* out = (float*)d_out;
  (void)in_sizes; (void)n_in; (void)out_size; (void)ws_size;

  float* ws      = (float*)d_ws;
  float* planesT = ws + WS_PLANES;
  float* feat    = ws + WS_FEAT;
  float* qk      = ws + WS_QK;
  float* aux     = ws + WS_AUX;
  float* wf      = ws + WS_WF;

  for (int pair = 0; pair < BS / PAIR_B; ++pair) {
    int b0 = pair * PAIR_B;
    hipLaunchKernelGGL(tpk2, dim3(3 * PAIR_B * 256), dim3(256), 0, stream,
                       cxz, cxy, cyz, planesT, b0);
    hipLaunchKernelGGL(featk, dim3(PAIR_Q / QT), dim3(256), 0, stream,
                       qp, planesT, w_off, b_off, w_q, b_q, w_k,
                       feat, aux, qk, b0);
    hipLaunchKernelGGL(attnk, dim3(PAIR_Q), dim3(256), 0, stream,
                       planesT, aux, qk, wf);
    hipLaunchKernelGGL(epik, dim3(PAIR_Q / QT), dim3(256), 0, stream,
                       wf, feat, w_v, b_v, w_out, b_out, out, b0);
  }
}